// Round 1
// baseline (1606.229 us; speedup 1.0000x reference)
//
#include <hip/hip_runtime.h>
#include <stdint.h>

#define AS1 __attribute__((address_space(1)))
#define AS3 __attribute__((address_space(3)))

typedef __bf16 bf8_t __attribute__((ext_vector_type(8)));
typedef float f4_t __attribute__((ext_vector_type(4)));

// ---------------- helpers ----------------
__device__ __forceinline__ unsigned short f2b(float f) {
  unsigned u = __builtin_bit_cast(unsigned, f);
  u += 0x7fffu + ((u >> 16) & 1u);          // RNE
  return (unsigned short)(u >> 16);
}
__device__ __forceinline__ void unpack8(uint4 u, float* dst) {
  unsigned a0 = u.x, a1 = u.y, a2 = u.z, a3 = u.w;
  dst[0] = __builtin_bit_cast(float, a0 << 16);
  dst[1] = __builtin_bit_cast(float, a0 & 0xffff0000u);
  dst[2] = __builtin_bit_cast(float, a1 << 16);
  dst[3] = __builtin_bit_cast(float, a1 & 0xffff0000u);
  dst[4] = __builtin_bit_cast(float, a2 << 16);
  dst[5] = __builtin_bit_cast(float, a2 & 0xffff0000u);
  dst[6] = __builtin_bit_cast(float, a3 << 16);
  dst[7] = __builtin_bit_cast(float, a3 & 0xffff0000u);
}

// ---------------- f32 -> bf16 convert ----------------
__global__ __launch_bounds__(256) void f2b_kernel(const float* __restrict__ in,
                                                  unsigned short* __restrict__ out, int n) {
  int i = (blockIdx.x * 256 + threadIdx.x) * 4;
  if (i >= n) return;
  float4 v = *(const float4*)(in + i);
  union { unsigned short u[4]; uint2 d; } p;
  p.u[0] = f2b(v.x); p.u[1] = f2b(v.y); p.u[2] = f2b(v.z); p.u[3] = f2b(v.w);
  *(uint2*)(out + i) = p.d;
}

// ---------------- LayerNorm (E=1024), f32 in -> bf16 out ----------------
__global__ __launch_bounds__(256) void ln_kernel(const float* __restrict__ x,
                                                 unsigned short* __restrict__ out) {
  const int row = blockIdx.x, tid = threadIdx.x;
  const float* xr = x + (size_t)row * 1024;
  float4 v = ((const float4*)xr)[tid];
  float s = v.x + v.y + v.z + v.w;
  float q = v.x * v.x + v.y * v.y + v.z * v.z + v.w * v.w;
  for (int o = 32; o; o >>= 1) { s += __shfl_down(s, o); q += __shfl_down(q, o); }
  __shared__ float rs[4], rq[4];
  const int w = tid >> 6;
  if ((tid & 63) == 0) { rs[w] = s; rq[w] = q; }
  __syncthreads();
  s = rs[0] + rs[1] + rs[2] + rs[3];
  q = rq[0] + rq[1] + rq[2] + rq[3];
  const float mean = s * (1.0f / 1024.0f);
  const float var = q * (1.0f / 1024.0f) - mean * mean;
  const float rstd = rsqrtf(var + 1e-5f);
  union { unsigned short u[4]; uint2 d; } p;
  p.u[0] = f2b((v.x - mean) * rstd);
  p.u[1] = f2b((v.y - mean) * rstd);
  p.u[2] = f2b((v.z - mean) * rstd);
  p.u[3] = f2b((v.w - mean) * rstd);
  *(uint2*)(out + (size_t)row * 1024 + tid * 4) = p.d;
}

// ---------------- GEMM: C[M,N] = A[M,K] @ W[N,K]^T (bf16 in, fp32 acc) ------
// m97 structure: 128x128 tile, BK=32, 4 waves (2x2), 4x4 16x16x32 frags/wave.
// EPI: 0 = store bf16; 1 = +resid -> f32; 2 = +bias, relu -> bf16; 3 = +bias +resid -> f32
template <int EPI>
__global__ __launch_bounds__(256, 2) void gemm_bt(
    const unsigned short* __restrict__ A, const unsigned short* __restrict__ Bw,
    int M, int N, int K,
    const float* __restrict__ bias, const float* __restrict__ resid,
    float* __restrict__ outF, unsigned short* __restrict__ outB) {
  __shared__ unsigned short As[128 * 32];
  __shared__ unsigned short Bs[128 * 32];
  const int tid = threadIdx.x;
  const int wave = tid >> 6, lane = tid & 63;
  const int bm = blockIdx.x, bn = blockIdx.y;
  const int wm = (wave & 1) * 64, wn = (wave >> 1) * 64;
  const int l16 = lane & 15, quad = lane >> 4;
  const int srow = lane >> 2;            // row within a 16-row staging chunk
  const int scol = (lane & 3) * 8;       // bf16-element col within BK=32

  const unsigned short* Abase = A + (size_t)(bm * 128) * K;
  const unsigned short* Bbase = Bw + (size_t)(bn * 128) * K;

  f4_t acc[4][4];
#pragma unroll
  for (int i = 0; i < 4; ++i)
#pragma unroll
    for (int j = 0; j < 4; ++j) acc[i][j] = (f4_t){0.f, 0.f, 0.f, 0.f};

  const int kiters = K >> 5;
  for (int k0 = 0; k0 < kiters; ++k0) {
    const int kk = k0 * 32;
#pragma unroll
    for (int i = 0; i < 2; ++i) {
      const int c = wave * 2 + i;  // 0..7 : 16-row chunk
      const unsigned short* ga = Abase + (size_t)(c * 16 + srow) * K + kk + scol;
      __builtin_amdgcn_global_load_lds((const AS1 void*)ga, (AS3 void*)(As + c * 512), 16, 0, 0);
      const unsigned short* gb = Bbase + (size_t)(c * 16 + srow) * K + kk + scol;
      __builtin_amdgcn_global_load_lds((const AS1 void*)gb, (AS3 void*)(Bs + c * 512), 16, 0, 0);
    }
    __syncthreads();
    bf8_t af[4], bfr[4];
#pragma unroll
    for (int mi = 0; mi < 4; ++mi)
      af[mi] = *(const bf8_t*)&As[(wm + mi * 16 + l16) * 32 + quad * 8];
#pragma unroll
    for (int ni = 0; ni < 4; ++ni)
      bfr[ni] = *(const bf8_t*)&Bs[(wn + ni * 16 + l16) * 32 + quad * 8];
#pragma unroll
    for (int mi = 0; mi < 4; ++mi)
#pragma unroll
      for (int ni = 0; ni < 4; ++ni)
        acc[mi][ni] =
            __builtin_amdgcn_mfma_f32_16x16x32_bf16(af[mi], bfr[ni], acc[mi][ni], 0, 0, 0);
    __syncthreads();
  }

#pragma unroll
  for (int mi = 0; mi < 4; ++mi) {
#pragma unroll
    for (int ni = 0; ni < 4; ++ni) {
      const int gm0 = bm * 128 + wm + mi * 16 + quad * 4;
      const int gn = bn * 128 + wn + ni * 16 + l16;
#pragma unroll
      for (int r = 0; r < 4; ++r) {
        float v = acc[mi][ni][r];
        const size_t idx = (size_t)(gm0 + r) * N + gn;
        if (EPI == 0) {
          outB[idx] = f2b(v);
        } else if (EPI == 1) {
          outF[idx] = v + resid[idx];
        } else if (EPI == 2) {
          v += bias[gn];
          outB[idx] = f2b(fmaxf(v, 0.0f));
        } else {
          v += bias[gn];
          outF[idx] = v + resid[idx];
        }
      }
    }
  }
}

// ---------------- causal flash attention (fp32 VALU) ----------------
// grid: (S/64, H, B), block 256. qkv bf16 [B*S, 3072]; o bf16 [B*S, 1024].
__global__ __launch_bounds__(256) void attn_kernel(const unsigned short* __restrict__ qkv,
                                                   unsigned short* __restrict__ o) {
  const int qb = blockIdx.x, h = blockIdx.y, b = blockIdx.z;
  const int tid = threadIdx.x;
  const int qbase = qb * 64;

  __shared__ float Ks[64][68];   // +4 pad: conflict-free score reads
  __shared__ float Vs[64][64];   // also reused as Q staging
  __shared__ float Ps[64][65];   // +1 pad: conflict-free row access
  __shared__ float alphaS[64];
  __shared__ float recipS[64];

  const int m = tid >> 2;        // owned q row (score + O phases)
  const int nsel = tid & 3;
  const int d0 = nsel * 16;      // owned d-range for O

  const unsigned short* qptr = qkv + (size_t)(b * 2048 + qbase) * 3072 + h * 64;
  // stage Q tile into Vs
#pragma unroll
  for (int i = 0; i < 2; ++i) {
    const int c = tid + i * 256;
    const int r = c >> 3, off = (c & 7) * 8;
    uint4 u = *(const uint4*)(qptr + (size_t)r * 3072 + off);
    unpack8(u, &Vs[r][off]);
  }
  __syncthreads();
  float4 Qreg[16];
  const float scale = 0.125f;    // 1/sqrt(64)
#pragma unroll
  for (int j = 0; j < 16; ++j) {
    float4 t = *(const float4*)&Vs[m][j * 4];
    Qreg[j] = make_float4(t.x * scale, t.y * scale, t.z * scale, t.w * scale);
  }

  float mi_s = -1e30f, li_s = 0.0f;  // valid in threads tid<64 (row = tid)
  float4 O[4];
  O[0] = O[1] = O[2] = O[3] = make_float4(0.f, 0.f, 0.f, 0.f);

  const int nkt = qb + 1;
  for (int kt = 0; kt < nkt; ++kt) {
    const int kbase = kt * 64;
    __syncthreads();  // previous readers of Ks/Vs/Ps done
    const unsigned short* kptr = qkv + (size_t)(b * 2048 + kbase) * 3072 + 1024 + h * 64;
    const unsigned short* vptr = qkv + (size_t)(b * 2048 + kbase) * 3072 + 2048 + h * 64;
#pragma unroll
    for (int i = 0; i < 2; ++i) {
      const int c = tid + i * 256;
      const int r = c >> 3, off = (c & 7) * 8;
      uint4 uk = *(const uint4*)(kptr + (size_t)r * 3072 + off);
      unpack8(uk, &Ks[r][off]);
      uint4 uv = *(const uint4*)(vptr + (size_t)r * 3072 + off);
      unpack8(uv, &Vs[r][off]);
    }
    __syncthreads();

    // scores: thread computes rows m, cols n = nsel + 4j
    const bool diag = (kt == qb);
#pragma unroll 4
    for (int j = 0; j < 16; ++j) {
      const int n = nsel + 4 * j;
      float s = 0.f;
#pragma unroll
      for (int dj = 0; dj < 16; ++dj) {
        float4 kv = *(const float4*)&Ks[n][dj * 4];
        float4 qv = Qreg[dj];
        s += qv.x * kv.x + qv.y * kv.y + qv.z * kv.z + qv.w * kv.w;
      }
      if (diag && (kbase + n > qbase + m)) s = -1e30f;
      Ps[m][n] = s;
    }
    __syncthreads();

    // online softmax (one thread per row)
    if (tid < 64) {
      const int mm = tid;
      float mx = -1e30f;
#pragma unroll 8
      for (int n = 0; n < 64; ++n) mx = fmaxf(mx, Ps[mm][n]);
      const float newm = fmaxf(mi_s, mx);
      const float alpha = __expf(mi_s - newm);
      float sum = 0.f;
#pragma unroll 8
      for (int n = 0; n < 64; ++n) {
        const float p = __expf(Ps[mm][n] - newm);
        Ps[mm][n] = p;
        sum += p;
      }
      li_s = li_s * alpha + sum;
      mi_s = newm;
      alphaS[mm] = alpha;
    }
    __syncthreads();

    // O update
    const float alpha = alphaS[m];
#pragma unroll
    for (int jj = 0; jj < 4; ++jj) {
      O[jj].x *= alpha; O[jj].y *= alpha; O[jj].z *= alpha; O[jj].w *= alpha;
    }
#pragma unroll 8
    for (int n = 0; n < 64; ++n) {
      const float p = Ps[m][n];
#pragma unroll
      for (int jj = 0; jj < 4; ++jj) {
        float4 vv = *(const float4*)&Vs[n][d0 + jj * 4];
        O[jj].x += p * vv.x; O[jj].y += p * vv.y; O[jj].z += p * vv.z; O[jj].w += p * vv.w;
      }
    }
  }
  __syncthreads();
  if (tid < 64) recipS[tid] = 1.0f / li_s;
  __syncthreads();
  const float rcp = recipS[m];

  unsigned short* optr = o + (size_t)(b * 2048 + qbase + m) * 1024 + h * 64 + d0;
  union { unsigned short u[16]; uint4 v[2]; } pk;
#pragma unroll
  for (int jj = 0; jj < 4; ++jj) {
    pk.u[jj * 4 + 0] = f2b(O[jj].x * rcp);
    pk.u[jj * 4 + 1] = f2b(O[jj].y * rcp);
    pk.u[jj * 4 + 2] = f2b(O[jj].z * rcp);
    pk.u[jj * 4 + 3] = f2b(O[jj].w * rcp);
  }
  *(uint4*)optr = pk.v[0];
  *((uint4*)optr + 1) = pk.v[1];
}

// ---------------- launcher ----------------
extern "C" void kernel_launch(void* const* d_in, const int* in_sizes, int n_in,
                              void* d_out, int out_size, void* d_ws, size_t ws_size,
                              hipStream_t stream) {
  const float* x = (const float*)d_in[0];       // [2,2048,1024]
  const float* w_in = (const float*)d_in[1];    // [3072,1024]
  const float* w_out = (const float*)d_in[2];   // [1024,1024]
  const float* w_fc = (const float*)d_in[3];    // [4096,1024]
  const float* b_fc = (const float*)d_in[4];    // [4096]
  const float* w_proj = (const float*)d_in[5];  // [1024,4096]
  const float* b_proj = (const float*)d_in[6];  // [1024]
  float* out = (float*)d_out;

  char* ws = (char*)d_ws;
  unsigned short* w_in_b = (unsigned short*)(ws);                  //  6 MB
  unsigned short* w_out_b = (unsigned short*)(ws + 6291456);       //  2 MB
  unsigned short* w_fc_b = (unsigned short*)(ws + 8388608);        //  8 MB
  unsigned short* w_proj_b = (unsigned short*)(ws + 16777216);     //  8 MB
  unsigned short* h_b = (unsigned short*)(ws + 25165824);          //  8 MB (ln1 & ln2)
  float* x2 = (float*)(ws + 33554432);                             // 16 MB
  unsigned short* qkv_b = (unsigned short*)(ws + 50331648);        // 24 MB
  unsigned short* o_b = (unsigned short*)(ws + 75497472);          //  8 MB
  unsigned short* m_b = (unsigned short*)(ws + 50331648);          // 32 MB, aliases qkv+o (dead by then)

  f2b_kernel<<<3072, 256, 0, stream>>>(w_in, w_in_b, 3145728);
  f2b_kernel<<<1024, 256, 0, stream>>>(w_out, w_out_b, 1048576);
  f2b_kernel<<<4096, 256, 0, stream>>>(w_fc, w_fc_b, 4194304);
  f2b_kernel<<<4096, 256, 0, stream>>>(w_proj, w_proj_b, 4194304);

  ln_kernel<<<4096, 256, 0, stream>>>(x, h_b);

  // qkv = h @ w_in^T : [4096,3072]
  gemm_bt<0><<<dim3(32, 24), 256, 0, stream>>>(h_b, w_in_b, 4096, 3072, 1024,
                                               nullptr, nullptr, nullptr, qkv_b);

  attn_kernel<<<dim3(32, 16, 2), 256, 0, stream>>>(qkv_b, o_b);

  // x2 = o @ w_out^T + x : [4096,1024] f32
  gemm_bt<1><<<dim3(32, 8), 256, 0, stream>>>(o_b, w_out_b, 4096, 1024, 1024,
                                              nullptr, x, x2, nullptr);

  ln_kernel<<<4096, 256, 0, stream>>>(x2, h_b);

  // m = relu(h2 @ w_fc^T + b_fc) : [4096,4096] bf16
  gemm_bt<2><<<dim3(32, 32), 256, 0, stream>>>(h_b, w_fc_b, 4096, 4096, 1024,
                                               b_fc, nullptr, nullptr, m_b);

  // out = m @ w_proj^T + b_proj + x2 : [4096,1024] f32
  gemm_bt<3><<<dim3(32, 8), 256, 0, stream>>>(m_b, w_proj_b, 4096, 1024, 4096,
                                              b_proj, x2, out, nullptr);
}

// Round 2
// 404.770 us; speedup vs baseline: 3.9682x; 3.9682x over previous
//
#include <hip/hip_runtime.h>
#include <stdint.h>

#define AS1 __attribute__((address_space(1)))
#define AS3 __attribute__((address_space(3)))

typedef __bf16 bf8_t __attribute__((ext_vector_type(8)));
typedef float f4_t __attribute__((ext_vector_type(4)));

// ---------------- helpers ----------------
__device__ __forceinline__ unsigned short f2b(float f) {
  unsigned u = __builtin_bit_cast(unsigned, f);
  u += 0x7fffu + ((u >> 16) & 1u);          // RNE
  return (unsigned short)(u >> 16);
}
__device__ __forceinline__ void unpack8(uint4 u, float* dst) {
  unsigned a0 = u.x, a1 = u.y, a2 = u.z, a3 = u.w;
  dst[0] = __builtin_bit_cast(float, a0 << 16);
  dst[1] = __builtin_bit_cast(float, a0 & 0xffff0000u);
  dst[2] = __builtin_bit_cast(float, a1 << 16);
  dst[3] = __builtin_bit_cast(float, a1 & 0xffff0000u);
  dst[4] = __builtin_bit_cast(float, a2 << 16);
  dst[5] = __builtin_bit_cast(float, a2 & 0xffff0000u);
  dst[6] = __builtin_bit_cast(float, a3 << 16);
  dst[7] = __builtin_bit_cast(float, a3 & 0xffff0000u);
}

// ---------------- f32 -> bf16 convert ----------------
__global__ __launch_bounds__(256) void f2b_kernel(const float* __restrict__ in,
                                                  unsigned short* __restrict__ out, int n) {
  int i = (blockIdx.x * 256 + threadIdx.x) * 4;
  if (i >= n) return;
  float4 v = *(const float4*)(in + i);
  union { unsigned short u[4]; uint2 d; } p;
  p.u[0] = f2b(v.x); p.u[1] = f2b(v.y); p.u[2] = f2b(v.z); p.u[3] = f2b(v.w);
  *(uint2*)(out + i) = p.d;
}

// ---------------- LayerNorm (E=1024), f32 in -> bf16 out ----------------
__global__ __launch_bounds__(256) void ln_kernel(const float* __restrict__ x,
                                                 unsigned short* __restrict__ out) {
  const int row = blockIdx.x, tid = threadIdx.x;
  const float* xr = x + (size_t)row * 1024;
  float4 v = ((const float4*)xr)[tid];
  float s = v.x + v.y + v.z + v.w;
  float q = v.x * v.x + v.y * v.y + v.z * v.z + v.w * v.w;
  for (int o = 32; o; o >>= 1) { s += __shfl_down(s, o); q += __shfl_down(q, o); }
  __shared__ float rs[4], rq[4];
  const int w = tid >> 6;
  if ((tid & 63) == 0) { rs[w] = s; rq[w] = q; }
  __syncthreads();
  s = rs[0] + rs[1] + rs[2] + rs[3];
  q = rq[0] + rq[1] + rq[2] + rq[3];
  const float mean = s * (1.0f / 1024.0f);
  const float var = q * (1.0f / 1024.0f) - mean * mean;
  const float rstd = rsqrtf(var + 1e-5f);
  union { unsigned short u[4]; uint2 d; } p;
  p.u[0] = f2b((v.x - mean) * rstd);
  p.u[1] = f2b((v.y - mean) * rstd);
  p.u[2] = f2b((v.z - mean) * rstd);
  p.u[3] = f2b((v.w - mean) * rstd);
  *(uint2*)(out + (size_t)row * 1024 + tid * 4) = p.d;
}

// ---------------- GEMM: C[M,N] = A[M,K] @ W[N,K]^T (bf16 in, fp32 acc) ------
template <int EPI>
__global__ __launch_bounds__(256, 2) void gemm_bt(
    const unsigned short* __restrict__ A, const unsigned short* __restrict__ Bw,
    int M, int N, int K,
    const float* __restrict__ bias, const float* __restrict__ resid,
    float* __restrict__ outF, unsigned short* __restrict__ outB) {
  __shared__ unsigned short As[128 * 32];
  __shared__ unsigned short Bs[128 * 32];
  const int tid = threadIdx.x;
  const int wave = tid >> 6, lane = tid & 63;
  const int bm = blockIdx.x, bn = blockIdx.y;
  const int wm = (wave & 1) * 64, wn = (wave >> 1) * 64;
  const int l16 = lane & 15, quad = lane >> 4;
  const int srow = lane >> 2;
  const int scol = (lane & 3) * 8;

  const unsigned short* Abase = A + (size_t)(bm * 128) * K;
  const unsigned short* Bbase = Bw + (size_t)(bn * 128) * K;

  f4_t acc[4][4];
#pragma unroll
  for (int i = 0; i < 4; ++i)
#pragma unroll
    for (int j = 0; j < 4; ++j) acc[i][j] = (f4_t){0.f, 0.f, 0.f, 0.f};

  const int kiters = K >> 5;
  for (int k0 = 0; k0 < kiters; ++k0) {
    const int kk = k0 * 32;
#pragma unroll
    for (int i = 0; i < 2; ++i) {
      const int c = wave * 2 + i;
      const unsigned short* ga = Abase + (size_t)(c * 16 + srow) * K + kk + scol;
      __builtin_amdgcn_global_load_lds((const AS1 void*)ga, (AS3 void*)(As + c * 512), 16, 0, 0);
      const unsigned short* gb = Bbase + (size_t)(c * 16 + srow) * K + kk + scol;
      __builtin_amdgcn_global_load_lds((const AS1 void*)gb, (AS3 void*)(Bs + c * 512), 16, 0, 0);
    }
    __syncthreads();
    bf8_t af[4], bfr[4];
#pragma unroll
    for (int mi = 0; mi < 4; ++mi)
      af[mi] = *(const bf8_t*)&As[(wm + mi * 16 + l16) * 32 + quad * 8];
#pragma unroll
    for (int ni = 0; ni < 4; ++ni)
      bfr[ni] = *(const bf8_t*)&Bs[(wn + ni * 16 + l16) * 32 + quad * 8];
#pragma unroll
    for (int mi = 0; mi < 4; ++mi)
#pragma unroll
      for (int ni = 0; ni < 4; ++ni)
        acc[mi][ni] =
            __builtin_amdgcn_mfma_f32_16x16x32_bf16(af[mi], bfr[ni], acc[mi][ni], 0, 0, 0);
    __syncthreads();
  }

#pragma unroll
  for (int mi = 0; mi < 4; ++mi) {
#pragma unroll
    for (int ni = 0; ni < 4; ++ni) {
      const int gm0 = bm * 128 + wm + mi * 16 + quad * 4;
      const int gn = bn * 128 + wn + ni * 16 + l16;
#pragma unroll
      for (int r = 0; r < 4; ++r) {
        float v = acc[mi][ni][r];
        const size_t idx = (size_t)(gm0 + r) * N + gn;
        if (EPI == 0) {
          outB[idx] = f2b(v);
        } else if (EPI == 1) {
          outF[idx] = v + resid[idx];
        } else if (EPI == 2) {
          v += bias[gn];
          outB[idx] = f2b(fmaxf(v, 0.0f));
        } else {
          v += bias[gn];
          outF[idx] = v + resid[idx];
        }
      }
    }
  }
}

// ---------------- MFMA causal flash attention ----------------
// grid (16, 16, 2) = (q-tile, head, batch); block 256 (4 waves).
// Q-tile 128 rows (wave owns 32), K-tile 64 cols, D = 64.
// S^T = K.Q^T via mfma (m=kcol, n=q) so P packs to LDS with b64 writes
// and re-reads as contiguous b128 A-fragments. V staged transposed with
// XOR swizzle (col ^ 8*(d>>3)) for conflict-light writes + b128 B-frags.
__global__ __launch_bounds__(256) void attn_kernel(const unsigned short* __restrict__ qkv,
                                                   unsigned short* __restrict__ o) {
  const int tq = 15 - blockIdx.x;  // heavy tiles dispatched first
  const int h = blockIdx.y, b = blockIdx.z;
  const int tid = threadIdx.x;
  const int wave = tid >> 6, lane = tid & 63;
  const int l15 = lane & 15, quad = lane >> 4;

  __shared__ __align__(16) unsigned short Ks[64 * 72];
  __shared__ __align__(16) unsigned short Vt[64 * 72];
  __shared__ __align__(16) unsigned short Ps[128 * 72];

  const int sr = tid >> 3;   // staging row 0..31 (+32 second iter)
  const int sd = tid & 7;    // staging d-chunk

  const size_t bh_base = ((size_t)b * 2048) * 3072 + h * 64;

  // ---- Q fragments (pre-scaled by 1/8, exact in bf16) ----
  bf8_t qf[2][2];
#pragma unroll
  for (int ni = 0; ni < 2; ++ni)
#pragma unroll
    for (int s = 0; s < 2; ++s) {
      const int qrow = tq * 128 + wave * 32 + ni * 16 + l15;
      uint4 u = *(const uint4*)(qkv + bh_base + (size_t)qrow * 3072 + s * 32 + quad * 8);
      float f[8]; unpack8(u, f);
      union { unsigned short us[8]; bf8_t v; } pk;
#pragma unroll
      for (int j = 0; j < 8; ++j) pk.us[j] = f2b(f[j] * 0.125f);
      qf[ni][s] = pk.v;
    }

  float m_s[2] = {-1e30f, -1e30f}, l_s[2] = {0.f, 0.f};
  f4_t O[2][4];
#pragma unroll
  for (int i = 0; i < 2; ++i)
#pragma unroll
    for (int j = 0; j < 4; ++j) O[i][j] = (f4_t){0.f, 0.f, 0.f, 0.f};

  const int qg0 = tq * 128 + wave * 32;
  const int nkt = 2 * tq + 2;
  for (int kt = 0; kt < nkt; ++kt) {
    __syncthreads();
    // ---- stage K (natural, pitch 72) and V (transposed + swizzled) ----
#pragma unroll
    for (int it = 0; it < 2; ++it) {
      const int r = sr + it * 32;
      const unsigned short* kp = qkv + bh_base + (size_t)(kt * 64 + r) * 3072 + 1024 + sd * 8;
      uint4 ku = *(const uint4*)kp;
      *(uint4*)&Ks[r * 72 + sd * 8] = ku;
      const unsigned short* vp = qkv + bh_base + (size_t)(kt * 64 + r) * 3072 + 2048 + sd * 8;
      uint4 vu = *(const uint4*)vp;
      union { unsigned short us[8]; uint4 v; } t; t.v = vu;
      const int rx = r ^ (sd * 8);
#pragma unroll
      for (int j = 0; j < 8; ++j) Vt[(sd * 8 + j) * 72 + rx] = t.us[j];
    }
    __syncthreads();

    const bool skip = (kt * 64 > qg0 + 31);  // fully-masked for this wave
    if (!skip) {
      // ---- S^T = K . Q^T ----
      f4_t S[4][2];
#pragma unroll
      for (int mi = 0; mi < 4; ++mi)
#pragma unroll
        for (int ni = 0; ni < 2; ++ni) S[mi][ni] = (f4_t){0.f, 0.f, 0.f, 0.f};
#pragma unroll
      for (int s = 0; s < 2; ++s)
#pragma unroll
        for (int mi = 0; mi < 4; ++mi) {
          bf8_t kf = *(const bf8_t*)&Ks[(mi * 16 + l15) * 72 + s * 32 + quad * 8];
#pragma unroll
          for (int ni = 0; ni < 2; ++ni)
            S[mi][ni] = __builtin_amdgcn_mfma_f32_16x16x32_bf16(kf, qf[ni][s], S[mi][ni], 0, 0, 0);
        }

      // ---- causal mask (diagonal tiles only) ----
      if (kt * 64 + 63 > qg0) {
#pragma unroll
        for (int mi = 0; mi < 4; ++mi)
#pragma unroll
          for (int ni = 0; ni < 2; ++ni)
#pragma unroll
            for (int r = 0; r < 4; ++r) {
              const int kg = kt * 64 + mi * 16 + quad * 4 + r;
              const int qg = qg0 + ni * 16 + l15;
              if (kg > qg) S[mi][ni][r] = -1e30f;
            }
      }

      // ---- online softmax (state per q = l15, duplicated across quads) ----
      float alpha[2];
#pragma unroll
      for (int ni = 0; ni < 2; ++ni) {
        float mx = -1e30f;
#pragma unroll
        for (int mi = 0; mi < 4; ++mi)
#pragma unroll
          for (int r = 0; r < 4; ++r) mx = fmaxf(mx, S[mi][ni][r]);
        mx = fmaxf(mx, __shfl_xor(mx, 16));
        mx = fmaxf(mx, __shfl_xor(mx, 32));
        const float mn = fmaxf(m_s[ni], mx);
        alpha[ni] = __expf(m_s[ni] - mn);
        float sum = 0.f;
#pragma unroll
        for (int mi = 0; mi < 4; ++mi)
#pragma unroll
          for (int r = 0; r < 4; ++r) {
            const float p = __expf(S[mi][ni][r] - mn);
            S[mi][ni][r] = p;
            sum += p;
          }
        sum += __shfl_xor(sum, 16);
        sum += __shfl_xor(sum, 32);
        m_s[ni] = mn;
        l_s[ni] = l_s[ni] * alpha[ni] + sum;
        // pack P -> LDS (rows = q, cols = kcol; 4 consecutive kcol per b64)
#pragma unroll
        for (int mi = 0; mi < 4; ++mi) {
          uint2 w2;
          w2.x = (unsigned)f2b(S[mi][ni][0]) | ((unsigned)f2b(S[mi][ni][1]) << 16);
          w2.y = (unsigned)f2b(S[mi][ni][2]) | ((unsigned)f2b(S[mi][ni][3]) << 16);
          *(uint2*)&Ps[(wave * 32 + ni * 16 + l15) * 72 + mi * 16 + quad * 4] = w2;
        }
      }

      // ---- PV: O += P . V  (X=P b128 frags, Y=V^T swizzled b128 frags) ----
      bf8_t pf[2][2], vf[4][2];
#pragma unroll
      for (int mi2 = 0; mi2 < 2; ++mi2)
#pragma unroll
        for (int s = 0; s < 2; ++s)
          pf[mi2][s] = *(const bf8_t*)&Ps[(wave * 32 + mi2 * 16 + l15) * 72 + s * 32 + quad * 8];
#pragma unroll
      for (int n4 = 0; n4 < 4; ++n4)
#pragma unroll
        for (int s = 0; s < 2; ++s) {
          const int swz = (2 * n4 + (l15 >> 3)) & 7;
          vf[n4][s] = *(const bf8_t*)&Vt[(n4 * 16 + l15) * 72 + 8 * ((4 * s + quad) ^ swz)];
        }
#pragma unroll
      for (int mi2 = 0; mi2 < 2; ++mi2) {
        float ar[4];
#pragma unroll
        for (int r = 0; r < 4; ++r) ar[r] = __shfl(alpha[mi2], quad * 4 + r);
#pragma unroll
        for (int n4 = 0; n4 < 4; ++n4) {
#pragma unroll
          for (int r = 0; r < 4; ++r) O[mi2][n4][r] *= ar[r];
#pragma unroll
          for (int s = 0; s < 2; ++s)
            O[mi2][n4] =
                __builtin_amdgcn_mfma_f32_16x16x32_bf16(pf[mi2][s], vf[n4][s], O[mi2][n4], 0, 0, 0);
        }
      }
    }
  }

  // ---- epilogue: O / l -> bf16 ----
#pragma unroll
  for (int mi2 = 0; mi2 < 2; ++mi2) {
    const float rc = 1.0f / l_s[mi2];
    float rr[4];
#pragma unroll
    for (int r = 0; r < 4; ++r) rr[r] = __shfl(rc, quad * 4 + r);
#pragma unroll
    for (int n4 = 0; n4 < 4; ++n4)
#pragma unroll
      for (int r = 0; r < 4; ++r) {
        const int qg = tq * 128 + wave * 32 + mi2 * 16 + quad * 4 + r;
        o[(size_t)(b * 2048 + qg) * 1024 + h * 64 + n4 * 16 + l15] = f2b(O[mi2][n4][r] * rr[r]);
      }
  }
}

// ---------------- launcher ----------------
extern "C" void kernel_launch(void* const* d_in, const int* in_sizes, int n_in,
                              void* d_out, int out_size, void* d_ws, size_t ws_size,
                              hipStream_t stream) {
  const float* x = (const float*)d_in[0];
  const float* w_in = (const float*)d_in[1];
  const float* w_out = (const float*)d_in[2];
  const float* w_fc = (const float*)d_in[3];
  const float* b_fc = (const float*)d_in[4];
  const float* w_proj = (const float*)d_in[5];
  const float* b_proj = (const float*)d_in[6];
  float* out = (float*)d_out;

  char* ws = (char*)d_ws;
  unsigned short* w_in_b = (unsigned short*)(ws);
  unsigned short* w_out_b = (unsigned short*)(ws + 6291456);
  unsigned short* w_fc_b = (unsigned short*)(ws + 8388608);
  unsigned short* w_proj_b = (unsigned short*)(ws + 16777216);
  unsigned short* h_b = (unsigned short*)(ws + 25165824);
  float* x2 = (float*)(ws + 33554432);
  unsigned short* qkv_b = (unsigned short*)(ws + 50331648);
  unsigned short* o_b = (unsigned short*)(ws + 75497472);
  unsigned short* m_b = (unsigned short*)(ws + 50331648);  // aliases qkv+o (dead by then)

  f2b_kernel<<<3072, 256, 0, stream>>>(w_in, w_in_b, 3145728);
  f2b_kernel<<<1024, 256, 0, stream>>>(w_out, w_out_b, 1048576);
  f2b_kernel<<<4096, 256, 0, stream>>>(w_fc, w_fc_b, 4194304);
  f2b_kernel<<<4096, 256, 0, stream>>>(w_proj, w_proj_b, 4194304);

  ln_kernel<<<4096, 256, 0, stream>>>(x, h_b);

  gemm_bt<0><<<dim3(32, 24), 256, 0, stream>>>(h_b, w_in_b, 4096, 3072, 1024,
                                               nullptr, nullptr, nullptr, qkv_b);

  attn_kernel<<<dim3(16, 16, 2), 256, 0, stream>>>(qkv_b, o_b);

  gemm_bt<1><<<dim3(32, 8), 256, 0, stream>>>(o_b, w_out_b, 4096, 1024, 1024,
                                              nullptr, x, x2, nullptr);

  ln_kernel<<<4096, 256, 0, stream>>>(x2, h_b);

  gemm_bt<2><<<dim3(32, 32), 256, 0, stream>>>(h_b, w_fc_b, 4096, 4096, 1024,
                                               b_fc, nullptr, nullptr, m_b);

  gemm_bt<3><<<dim3(32, 8), 256, 0, stream>>>(m_b, w_proj_b, 4096, 1024, 4096,
                                              b_proj, x2, out, nullptr);
}

// Round 3
// 382.704 us; speedup vs baseline: 4.1971x; 1.0577x over previous
//
#include <hip/hip_runtime.h>
#include <stdint.h>

#define AS1 __attribute__((address_space(1)))
#define AS3 __attribute__((address_space(3)))

typedef __bf16 bf8_t __attribute__((ext_vector_type(8)));
typedef float f4_t __attribute__((ext_vector_type(4)));

// ---------------- helpers ----------------
__device__ __forceinline__ unsigned short f2b(float f) {
  unsigned u = __builtin_bit_cast(unsigned, f);
  u += 0x7fffu + ((u >> 16) & 1u);          // RNE
  return (unsigned short)(u >> 16);
}
__device__ __forceinline__ void unpack8(uint4 u, float* dst) {
  unsigned a0 = u.x, a1 = u.y, a2 = u.z, a3 = u.w;
  dst[0] = __builtin_bit_cast(float, a0 << 16);
  dst[1] = __builtin_bit_cast(float, a0 & 0xffff0000u);
  dst[2] = __builtin_bit_cast(float, a1 << 16);
  dst[3] = __builtin_bit_cast(float, a1 & 0xffff0000u);
  dst[4] = __builtin_bit_cast(float, a2 << 16);
  dst[5] = __builtin_bit_cast(float, a2 & 0xffff0000u);
  dst[6] = __builtin_bit_cast(float, a3 << 16);
  dst[7] = __builtin_bit_cast(float, a3 & 0xffff0000u);
}

// ---------------- f32 -> bf16 convert ----------------
__global__ __launch_bounds__(256) void f2b_kernel(const float* __restrict__ in,
                                                  unsigned short* __restrict__ out, int n) {
  int i = (blockIdx.x * 256 + threadIdx.x) * 4;
  if (i >= n) return;
  float4 v = *(const float4*)(in + i);
  union { unsigned short u[4]; uint2 d; } p;
  p.u[0] = f2b(v.x); p.u[1] = f2b(v.y); p.u[2] = f2b(v.z); p.u[3] = f2b(v.w);
  *(uint2*)(out + i) = p.d;
}

// ---------------- LayerNorm (E=1024), f32 in -> bf16 out ----------------
__global__ __launch_bounds__(256) void ln_kernel(const float* __restrict__ x,
                                                 unsigned short* __restrict__ out) {
  const int row = blockIdx.x, tid = threadIdx.x;
  const float* xr = x + (size_t)row * 1024;
  float4 v = ((const float4*)xr)[tid];
  float s = v.x + v.y + v.z + v.w;
  float q = v.x * v.x + v.y * v.y + v.z * v.z + v.w * v.w;
  for (int o = 32; o; o >>= 1) { s += __shfl_down(s, o); q += __shfl_down(q, o); }
  __shared__ float rs[4], rq[4];
  const int w = tid >> 6;
  if ((tid & 63) == 0) { rs[w] = s; rq[w] = q; }
  __syncthreads();
  s = rs[0] + rs[1] + rs[2] + rs[3];
  q = rq[0] + rq[1] + rq[2] + rq[3];
  const float mean = s * (1.0f / 1024.0f);
  const float var = q * (1.0f / 1024.0f) - mean * mean;
  const float rstd = rsqrtf(var + 1e-5f);
  union { unsigned short u[4]; uint2 d; } p;
  p.u[0] = f2b((v.x - mean) * rstd);
  p.u[1] = f2b((v.y - mean) * rstd);
  p.u[2] = f2b((v.z - mean) * rstd);
  p.u[3] = f2b((v.w - mean) * rstd);
  *(uint2*)(out + (size_t)row * 1024 + tid * 4) = p.d;
}

// ---------------- GEMM: C[M,N] = A[M,K] @ W[N,K]^T (bf16 in, fp32 acc) ------
template <int EPI>
__global__ __launch_bounds__(256, 2) void gemm_bt(
    const unsigned short* __restrict__ A, const unsigned short* __restrict__ Bw,
    int M, int N, int K,
    const float* __restrict__ bias, const float* __restrict__ resid,
    float* __restrict__ outF, unsigned short* __restrict__ outB) {
  __shared__ unsigned short As[128 * 32];
  __shared__ unsigned short Bs[128 * 32];
  const int tid = threadIdx.x;
  const int wave = tid >> 6, lane = tid & 63;
  const int bm = blockIdx.x, bn = blockIdx.y;
  const int wm = (wave & 1) * 64, wn = (wave >> 1) * 64;
  const int l16 = lane & 15, quad = lane >> 4;
  const int srow = lane >> 2;
  const int scol = (lane & 3) * 8;

  const unsigned short* Abase = A + (size_t)(bm * 128) * K;
  const unsigned short* Bbase = Bw + (size_t)(bn * 128) * K;

  f4_t acc[4][4];
#pragma unroll
  for (int i = 0; i < 4; ++i)
#pragma unroll
    for (int j = 0; j < 4; ++j) acc[i][j] = (f4_t){0.f, 0.f, 0.f, 0.f};

  const int kiters = K >> 5;
  for (int k0 = 0; k0 < kiters; ++k0) {
    const int kk = k0 * 32;
#pragma unroll
    for (int i = 0; i < 2; ++i) {
      const int c = wave * 2 + i;
      const unsigned short* ga = Abase + (size_t)(c * 16 + srow) * K + kk + scol;
      __builtin_amdgcn_global_load_lds((const AS1 void*)ga, (AS3 void*)(As + c * 512), 16, 0, 0);
      const unsigned short* gb = Bbase + (size_t)(c * 16 + srow) * K + kk + scol;
      __builtin_amdgcn_global_load_lds((const AS1 void*)gb, (AS3 void*)(Bs + c * 512), 16, 0, 0);
    }
    __syncthreads();
    bf8_t af[4], bfr[4];
#pragma unroll
    for (int mi = 0; mi < 4; ++mi)
      af[mi] = *(const bf8_t*)&As[(wm + mi * 16 + l16) * 32 + quad * 8];
#pragma unroll
    for (int ni = 0; ni < 4; ++ni)
      bfr[ni] = *(const bf8_t*)&Bs[(wn + ni * 16 + l16) * 32 + quad * 8];
#pragma unroll
    for (int mi = 0; mi < 4; ++mi)
#pragma unroll
      for (int ni = 0; ni < 4; ++ni)
        acc[mi][ni] =
            __builtin_amdgcn_mfma_f32_16x16x32_bf16(af[mi], bfr[ni], acc[mi][ni], 0, 0, 0);
    __syncthreads();
  }

#pragma unroll
  for (int mi = 0; mi < 4; ++mi) {
#pragma unroll
    for (int ni = 0; ni < 4; ++ni) {
      const int gm0 = bm * 128 + wm + mi * 16 + quad * 4;
      const int gn = bn * 128 + wn + ni * 16 + l16;
#pragma unroll
      for (int r = 0; r < 4; ++r) {
        float v = acc[mi][ni][r];
        const size_t idx = (size_t)(gm0 + r) * N + gn;
        if (EPI == 0) {
          outB[idx] = f2b(v);
        } else if (EPI == 1) {
          outF[idx] = v + resid[idx];
        } else if (EPI == 2) {
          v += bias[gn];
          outB[idx] = f2b(fmaxf(v, 0.0f));
        } else {
          v += bias[gn];
          outF[idx] = v + resid[idx];
        }
      }
    }
  }
}

// ---------------- MFMA causal flash attention ----------------
// grid (32, 16, 2) = (q-tile, head, batch); block 256 (4 waves).
// Q-tile 64 rows (wave owns 16), K-tile 64 cols, D = 64.
// 27.6 KB LDS -> 5 blocks/CU resident; cross-block overlap hides staging
// latency + barrier drains. Layouts identical to the R2-verified kernel.
__global__ __launch_bounds__(256, 5) void attn_kernel(const unsigned short* __restrict__ qkv,
                                                      unsigned short* __restrict__ o) {
  const int tq = 31 - blockIdx.x;  // heavy tiles dispatched first
  const int h = blockIdx.y, b = blockIdx.z;
  const int tid = threadIdx.x;
  const int wave = tid >> 6, lane = tid & 63;
  const int l15 = lane & 15, quad = lane >> 4;

  __shared__ __align__(16) unsigned short Ks[64 * 72];
  __shared__ __align__(16) unsigned short Vt[64 * 72];
  __shared__ __align__(16) unsigned short Ps[64 * 72];

  const int sr = tid >> 3;   // staging row 0..31 (+32 second iter)
  const int sd = tid & 7;    // staging d-chunk

  const size_t bh_base = ((size_t)b * 2048) * 3072 + h * 64;

  // ---- Q fragments (pre-scaled by 1/8, exact in bf16) ----
  bf8_t qf[2];
  {
    const int qrow = tq * 64 + wave * 16 + l15;
#pragma unroll
    for (int s = 0; s < 2; ++s) {
      uint4 u = *(const uint4*)(qkv + bh_base + (size_t)qrow * 3072 + s * 32 + quad * 8);
      float f[8]; unpack8(u, f);
      union { unsigned short us[8]; bf8_t v; } pk;
#pragma unroll
      for (int j = 0; j < 8; ++j) pk.us[j] = f2b(f[j] * 0.125f);
      qf[s] = pk.v;
    }
  }

  float m_s = -1e30f, l_s = 0.f;
  f4_t O[4];
#pragma unroll
  for (int j = 0; j < 4; ++j) O[j] = (f4_t){0.f, 0.f, 0.f, 0.f};

  const int qw0 = tq * 64 + wave * 16;
  const int nkt = tq + 1;
  for (int kt = 0; kt < nkt; ++kt) {
    __syncthreads();
    // ---- stage K (natural, pitch 72) and V (transposed + swizzled) ----
#pragma unroll
    for (int it = 0; it < 2; ++it) {
      const int r = sr + it * 32;
      uint4 ku = *(const uint4*)(qkv + bh_base + (size_t)(kt * 64 + r) * 3072 + 1024 + sd * 8);
      *(uint4*)&Ks[r * 72 + sd * 8] = ku;
      uint4 vu = *(const uint4*)(qkv + bh_base + (size_t)(kt * 64 + r) * 3072 + 2048 + sd * 8);
      union { unsigned short us[8]; uint4 v; } t; t.v = vu;
      const int rx = r ^ (sd * 8);
#pragma unroll
      for (int j = 0; j < 8; ++j) Vt[(sd * 8 + j) * 72 + rx] = t.us[j];
    }
    __syncthreads();

    // ---- S^T = K . Q^T ----
    f4_t S[4];
#pragma unroll
    for (int mi = 0; mi < 4; ++mi) S[mi] = (f4_t){0.f, 0.f, 0.f, 0.f};
#pragma unroll
    for (int s = 0; s < 2; ++s)
#pragma unroll
      for (int mi = 0; mi < 4; ++mi) {
        bf8_t kf = *(const bf8_t*)&Ks[(mi * 16 + l15) * 72 + s * 32 + quad * 8];
        S[mi] = __builtin_amdgcn_mfma_f32_16x16x32_bf16(kf, qf[s], S[mi], 0, 0, 0);
      }

    // ---- causal mask (diagonal tile only) ----
    if (kt == tq) {
#pragma unroll
      for (int mi = 0; mi < 4; ++mi)
#pragma unroll
        for (int r = 0; r < 4; ++r) {
          const int kg = kt * 64 + mi * 16 + quad * 4 + r;
          const int qg = qw0 + l15;
          if (kg > qg) S[mi][r] = -1e30f;
        }
    }

    // ---- online softmax (state per q = l15, duplicated across quads) ----
    float mx = -1e30f;
#pragma unroll
    for (int mi = 0; mi < 4; ++mi)
#pragma unroll
      for (int r = 0; r < 4; ++r) mx = fmaxf(mx, S[mi][r]);
    mx = fmaxf(mx, __shfl_xor(mx, 16));
    mx = fmaxf(mx, __shfl_xor(mx, 32));
    const float mn = fmaxf(m_s, mx);
    const float alpha = __expf(m_s - mn);
    float sum = 0.f;
#pragma unroll
    for (int mi = 0; mi < 4; ++mi)
#pragma unroll
      for (int r = 0; r < 4; ++r) {
        const float p = __expf(S[mi][r] - mn);
        S[mi][r] = p;
        sum += p;
      }
    sum += __shfl_xor(sum, 16);
    sum += __shfl_xor(sum, 32);
    m_s = mn;
    l_s = l_s * alpha + sum;
    // pack P -> LDS (row = q, col = kcol; per-wave-private rows, no barrier)
#pragma unroll
    for (int mi = 0; mi < 4; ++mi) {
      uint2 w2;
      w2.x = (unsigned)f2b(S[mi][0]) | ((unsigned)f2b(S[mi][1]) << 16);
      w2.y = (unsigned)f2b(S[mi][2]) | ((unsigned)f2b(S[mi][3]) << 16);
      *(uint2*)&Ps[(wave * 16 + l15) * 72 + mi * 16 + quad * 4] = w2;
    }

    // ---- PV: O += P . V ----
    bf8_t pf[2], vf[4][2];
#pragma unroll
    for (int s = 0; s < 2; ++s)
      pf[s] = *(const bf8_t*)&Ps[(wave * 16 + l15) * 72 + s * 32 + quad * 8];
#pragma unroll
    for (int n4 = 0; n4 < 4; ++n4)
#pragma unroll
      for (int s = 0; s < 2; ++s) {
        const int swz = (2 * n4 + (l15 >> 3)) & 7;
        vf[n4][s] = *(const bf8_t*)&Vt[(n4 * 16 + l15) * 72 + 8 * ((4 * s + quad) ^ swz)];
      }
    float ar[4];
#pragma unroll
    for (int r = 0; r < 4; ++r) ar[r] = __shfl(alpha, quad * 4 + r);
#pragma unroll
    for (int n4 = 0; n4 < 4; ++n4) {
#pragma unroll
      for (int r = 0; r < 4; ++r) O[n4][r] *= ar[r];
#pragma unroll
      for (int s = 0; s < 2; ++s)
        O[n4] = __builtin_amdgcn_mfma_f32_16x16x32_bf16(pf[s], vf[n4][s], O[n4], 0, 0, 0);
    }
  }

  // ---- epilogue: O / l -> bf16 ----
  const float rc = 1.0f / l_s;
  float rr[4];
#pragma unroll
  for (int r = 0; r < 4; ++r) rr[r] = __shfl(rc, quad * 4 + r);
#pragma unroll
  for (int n4 = 0; n4 < 4; ++n4)
#pragma unroll
    for (int r = 0; r < 4; ++r) {
      const int qg = tq * 64 + wave * 16 + quad * 4 + r;
      o[(size_t)(b * 2048 + qg) * 1024 + h * 64 + n4 * 16 + l15] = f2b(O[n4][r] * rr[r]);
    }
}

// ---------------- launcher ----------------
extern "C" void kernel_launch(void* const* d_in, const int* in_sizes, int n_in,
                              void* d_out, int out_size, void* d_ws, size_t ws_size,
                              hipStream_t stream) {
  const float* x = (const float*)d_in[0];
  const float* w_in = (const float*)d_in[1];
  const float* w_out = (const float*)d_in[2];
  const float* w_fc = (const float*)d_in[3];
  const float* b_fc = (const float*)d_in[4];
  const float* w_proj = (const float*)d_in[5];
  const float* b_proj = (const float*)d_in[6];
  float* out = (float*)d_out;

  char* ws = (char*)d_ws;
  unsigned short* w_in_b = (unsigned short*)(ws);
  unsigned short* w_out_b = (unsigned short*)(ws + 6291456);
  unsigned short* w_fc_b = (unsigned short*)(ws + 8388608);
  unsigned short* w_proj_b = (unsigned short*)(ws + 16777216);
  unsigned short* h_b = (unsigned short*)(ws + 25165824);
  float* x2 = (float*)(ws + 33554432);
  unsigned short* qkv_b = (unsigned short*)(ws + 50331648);
  unsigned short* o_b = (unsigned short*)(ws + 75497472);
  unsigned short* m_b = (unsigned short*)(ws + 50331648);  // aliases qkv+o (dead by then)

  f2b_kernel<<<3072, 256, 0, stream>>>(w_in, w_in_b, 3145728);
  f2b_kernel<<<1024, 256, 0, stream>>>(w_out, w_out_b, 1048576);
  f2b_kernel<<<4096, 256, 0, stream>>>(w_fc, w_fc_b, 4194304);
  f2b_kernel<<<4096, 256, 0, stream>>>(w_proj, w_proj_b, 4194304);

  ln_kernel<<<4096, 256, 0, stream>>>(x, h_b);

  gemm_bt<0><<<dim3(32, 24), 256, 0, stream>>>(h_b, w_in_b, 4096, 3072, 1024,
                                               nullptr, nullptr, nullptr, qkv_b);

  attn_kernel<<<dim3(32, 16, 2), 256, 0, stream>>>(qkv_b, o_b);

  gemm_bt<1><<<dim3(32, 8), 256, 0, stream>>>(o_b, w_out_b, 4096, 1024, 1024,
                                              nullptr, x, x2, nullptr);

  ln_kernel<<<4096, 256, 0, stream>>>(x2, h_b);

  gemm_bt<2><<<dim3(32, 32), 256, 0, stream>>>(h_b, w_fc_b, 4096, 4096, 1024,
                                               b_fc, nullptr, nullptr, m_b);

  gemm_bt<3><<<dim3(32, 8), 256, 0, stream>>>(m_b, w_proj_b, 4096, 1024, 4096,
                                              b_proj, x2, out, nullptr);
}

// Round 4
// 361.661 us; speedup vs baseline: 4.4413x; 1.0582x over previous
//
#include <hip/hip_runtime.h>
#include <stdint.h>

#define AS1 __attribute__((address_space(1)))
#define AS3 __attribute__((address_space(3)))

typedef __bf16 bf8_t __attribute__((ext_vector_type(8)));
typedef float f4_t __attribute__((ext_vector_type(4)));

// ---------------- helpers ----------------
__device__ __forceinline__ unsigned short f2b(float f) {
  unsigned u = __builtin_bit_cast(unsigned, f);
  u += 0x7fffu + ((u >> 16) & 1u);          // RNE
  return (unsigned short)(u >> 16);
}
__device__ __forceinline__ void unpack8(uint4 u, float* dst) {
  unsigned a0 = u.x, a1 = u.y, a2 = u.z, a3 = u.w;
  dst[0] = __builtin_bit_cast(float, a0 << 16);
  dst[1] = __builtin_bit_cast(float, a0 & 0xffff0000u);
  dst[2] = __builtin_bit_cast(float, a1 << 16);
  dst[3] = __builtin_bit_cast(float, a1 & 0xffff0000u);
  dst[4] = __builtin_bit_cast(float, a2 << 16);
  dst[5] = __builtin_bit_cast(float, a2 & 0xffff0000u);
  dst[6] = __builtin_bit_cast(float, a3 << 16);
  dst[7] = __builtin_bit_cast(float, a3 & 0xffff0000u);
}

// ---------------- f32 -> bf16 convert ----------------
__global__ __launch_bounds__(256) void f2b_kernel(const float* __restrict__ in,
                                                  unsigned short* __restrict__ out, int n) {
  int i = (blockIdx.x * 256 + threadIdx.x) * 4;
  if (i >= n) return;
  float4 v = *(const float4*)(in + i);
  union { unsigned short u[4]; uint2 d; } p;
  p.u[0] = f2b(v.x); p.u[1] = f2b(v.y); p.u[2] = f2b(v.z); p.u[3] = f2b(v.w);
  *(uint2*)(out + i) = p.d;
}

// ---------------- LayerNorm (E=1024), f32 in -> bf16 out ----------------
__global__ __launch_bounds__(256) void ln_kernel(const float* __restrict__ x,
                                                 unsigned short* __restrict__ out) {
  const int row = blockIdx.x, tid = threadIdx.x;
  const float* xr = x + (size_t)row * 1024;
  float4 v = ((const float4*)xr)[tid];
  float s = v.x + v.y + v.z + v.w;
  float q = v.x * v.x + v.y * v.y + v.z * v.z + v.w * v.w;
  for (int o = 32; o; o >>= 1) { s += __shfl_down(s, o); q += __shfl_down(q, o); }
  __shared__ float rs[4], rq[4];
  const int w = tid >> 6;
  if ((tid & 63) == 0) { rs[w] = s; rq[w] = q; }
  __syncthreads();
  s = rs[0] + rs[1] + rs[2] + rs[3];
  q = rq[0] + rq[1] + rq[2] + rq[3];
  const float mean = s * (1.0f / 1024.0f);
  const float var = q * (1.0f / 1024.0f) - mean * mean;
  const float rstd = rsqrtf(var + 1e-5f);
  union { unsigned short u[4]; uint2 d; } p;
  p.u[0] = f2b((v.x - mean) * rstd);
  p.u[1] = f2b((v.y - mean) * rstd);
  p.u[2] = f2b((v.z - mean) * rstd);
  p.u[3] = f2b((v.w - mean) * rstd);
  *(uint2*)(out + (size_t)row * 1024 + tid * 4) = p.d;
}

// ---------------- GEMM: C[M,N] = A[M,K] @ W[N,K]^T (bf16 in, fp32 acc) ------
template <int EPI>
__global__ __launch_bounds__(256, 2) void gemm_bt(
    const unsigned short* __restrict__ A, const unsigned short* __restrict__ Bw,
    int M, int N, int K,
    const float* __restrict__ bias, const float* __restrict__ resid,
    float* __restrict__ outF, unsigned short* __restrict__ outB) {
  __shared__ unsigned short As[128 * 32];
  __shared__ unsigned short Bs[128 * 32];
  const int tid = threadIdx.x;
  const int wave = tid >> 6, lane = tid & 63;
  const int bm = blockIdx.x, bn = blockIdx.y;
  const int wm = (wave & 1) * 64, wn = (wave >> 1) * 64;
  const int l16 = lane & 15, quad = lane >> 4;
  const int srow = lane >> 2;
  const int scol = (lane & 3) * 8;

  const unsigned short* Abase = A + (size_t)(bm * 128) * K;
  const unsigned short* Bbase = Bw + (size_t)(bn * 128) * K;

  f4_t acc[4][4];
#pragma unroll
  for (int i = 0; i < 4; ++i)
#pragma unroll
    for (int j = 0; j < 4; ++j) acc[i][j] = (f4_t){0.f, 0.f, 0.f, 0.f};

  const int kiters = K >> 5;
  for (int k0 = 0; k0 < kiters; ++k0) {
    const int kk = k0 * 32;
#pragma unroll
    for (int i = 0; i < 2; ++i) {
      const int c = wave * 2 + i;
      const unsigned short* ga = Abase + (size_t)(c * 16 + srow) * K + kk + scol;
      __builtin_amdgcn_global_load_lds((const AS1 void*)ga, (AS3 void*)(As + c * 512), 16, 0, 0);
      const unsigned short* gb = Bbase + (size_t)(c * 16 + srow) * K + kk + scol;
      __builtin_amdgcn_global_load_lds((const AS1 void*)gb, (AS3 void*)(Bs + c * 512), 16, 0, 0);
    }
    __syncthreads();
    bf8_t af[4], bfr[4];
#pragma unroll
    for (int mi = 0; mi < 4; ++mi)
      af[mi] = *(const bf8_t*)&As[(wm + mi * 16 + l16) * 32 + quad * 8];
#pragma unroll
    for (int ni = 0; ni < 4; ++ni)
      bfr[ni] = *(const bf8_t*)&Bs[(wn + ni * 16 + l16) * 32 + quad * 8];
#pragma unroll
    for (int mi = 0; mi < 4; ++mi)
#pragma unroll
      for (int ni = 0; ni < 4; ++ni)
        acc[mi][ni] =
            __builtin_amdgcn_mfma_f32_16x16x32_bf16(af[mi], bfr[ni], acc[mi][ni], 0, 0, 0);
    __syncthreads();
  }

#pragma unroll
  for (int mi = 0; mi < 4; ++mi) {
#pragma unroll
    for (int ni = 0; ni < 4; ++ni) {
      const int gm0 = bm * 128 + wm + mi * 16 + quad * 4;
      const int gn = bn * 128 + wn + ni * 16 + l16;
#pragma unroll
      for (int r = 0; r < 4; ++r) {
        float v = acc[mi][ni][r];
        const size_t idx = (size_t)(gm0 + r) * N + gn;
        if (EPI == 0) {
          outB[idx] = f2b(v);
        } else if (EPI == 1) {
          outF[idx] = v + resid[idx];
        } else if (EPI == 2) {
          v += bias[gn];
          outB[idx] = f2b(fmaxf(v, 0.0f));
        } else {
          v += bias[gn];
          outF[idx] = v + resid[idx];
        }
      }
    }
  }
}

// ---------------- K/V tile pre-pack ----------------
// grid 1024 = (b,h,kt); builds contiguous 8KB tiles that are byte-exact LDS
// images for global_load_lds staging in attn.
// K tile: pos (r, c) 16B chunk = K_scaled[r][8*(c ^ (r&7)) .. +8], K_scaled = K/8.
// V tile: pos (d, c) 16B chunk = V[8*(c ^ (d&7)) + j][d], j=0..7 (transposed).
__global__ __launch_bounds__(256) void pack_kv(const unsigned short* __restrict__ qkv,
                                               unsigned short* __restrict__ Kp,
                                               unsigned short* __restrict__ Vp) {
  const int lin = blockIdx.x;
  const int kt = lin & 31, h = (lin >> 5) & 15, b = lin >> 9;
  const int tid = threadIdx.x;
  __shared__ unsigned short Vs[64 * 72];
  const size_t rowbase = (size_t)(b * 2048 + kt * 64) * 3072 + h * 64;
  unsigned short* Kt = Kp + (size_t)lin * 4096;
  unsigned short* Vt = Vp + (size_t)lin * 4096;

  const int r0 = tid >> 3, cin = tid & 7;
#pragma unroll
  for (int it = 0; it < 2; ++it) {
    const int r = r0 + it * 32;
    uint4 ku = *(const uint4*)(qkv + rowbase + (size_t)r * 3072 + 1024 + cin * 8);
    float f[8]; unpack8(ku, f);
    union { unsigned short us[8]; uint4 v; } pk;
#pragma unroll
    for (int j = 0; j < 8; ++j) pk.us[j] = f2b(f[j] * 0.125f);
    *(uint4*)(Kt + (size_t)(r * 8 + (cin ^ (r & 7))) * 8) = pk.v;
    uint4 vu = *(const uint4*)(qkv + rowbase + (size_t)r * 3072 + 2048 + cin * 8);
    *(uint4*)&Vs[r * 72 + cin * 8] = vu;
  }
  __syncthreads();
#pragma unroll
  for (int oc2 = 0; oc2 < 2; ++oc2) {
    const int oc = tid * 2 + oc2;
    const int d = oc >> 3, c = oc & 7;
    const int k0 = 8 * (c ^ (d & 7));
    union { unsigned short us[8]; uint4 v; } pk;
#pragma unroll
    for (int j = 0; j < 8; ++j) pk.us[j] = Vs[(k0 + j) * 72 + d];
    *(uint4*)(Vt + (size_t)oc * 8) = pk.v;
  }
}

// ---------------- MFMA causal flash attention ----------------
// 1D grid 1024: b=lin&1, h=(lin>>1)&15, tq=lin>>5. Blocks sharing a CU
// (lin = c mod 256) get tq {t,t+8,t+16,t+24} -> per-CU work in [52,80] ktiles
// (was [4,128] -> tail). K/V staged via global_load_lds from pre-packed
// swizzled tiles (zero VALU staging work).
__global__ __launch_bounds__(256, 4) void attn_kernel(const unsigned short* __restrict__ qkv,
                                                      const unsigned short* __restrict__ Kp,
                                                      const unsigned short* __restrict__ Vp,
                                                      unsigned short* __restrict__ o) {
  const int lin = blockIdx.x;
  const int b = lin & 1, h = (lin >> 1) & 15, tq = lin >> 5;
  const int tid = threadIdx.x;
  const int wave = tid >> 6, lane = tid & 63;
  const int l15 = lane & 15, quad = lane >> 4;

  __shared__ __align__(16) unsigned short Ks[64 * 64];
  __shared__ __align__(16) unsigned short Vt[64 * 64];
  __shared__ __align__(16) unsigned short Ps[64 * 72];

  // ---- Q fragments (K pre-scaled by 1/8; Q loads raw bf16) ----
  bf8_t qf[2];
  {
    const int qrow = b * 2048 + tq * 64 + wave * 16 + l15;
#pragma unroll
    for (int s = 0; s < 2; ++s) {
      union { uint4 u; bf8_t v; } pk;
      pk.u = *(const uint4*)(qkv + (size_t)qrow * 3072 + h * 64 + s * 32 + quad * 8);
      qf[s] = pk.v;
    }
  }

  float m_s = -1e30f, l_s = 0.f;
  f4_t O[4];
#pragma unroll
  for (int j = 0; j < 4; ++j) O[j] = (f4_t){0.f, 0.f, 0.f, 0.f};

  const int qw0 = tq * 64 + wave * 16;
  const int swz = (l15 & 7) * 8;  // xor key for swizzled fragment reads
  const size_t tile0 = (size_t)((b * 16 + h) * 32) * 4096;

  for (int kt = 0; kt <= tq; ++kt) {
    __syncthreads();  // all waves done reading previous K/V tile
    const unsigned short* Ktile = Kp + tile0 + (size_t)kt * 4096;
    const unsigned short* Vtile = Vp + tile0 + (size_t)kt * 4096;
#pragma unroll
    for (int i = 0; i < 2; ++i) {
      const int seg = wave * 2 + i;
      __builtin_amdgcn_global_load_lds((const AS1 void*)(Ktile + seg * 512 + lane * 8),
                                       (AS3 void*)(Ks + seg * 512), 16, 0, 0);
      __builtin_amdgcn_global_load_lds((const AS1 void*)(Vtile + seg * 512 + lane * 8),
                                       (AS3 void*)(Vt + seg * 512), 16, 0, 0);
    }
    __syncthreads();

    // ---- S^T = K . Q^T ----
    f4_t S[4];
#pragma unroll
    for (int mi = 0; mi < 4; ++mi) S[mi] = (f4_t){0.f, 0.f, 0.f, 0.f};
#pragma unroll
    for (int s = 0; s < 2; ++s)
#pragma unroll
      for (int mi = 0; mi < 4; ++mi) {
        bf8_t kf = *(const bf8_t*)&Ks[(mi * 16 + l15) * 64 + (((4 * s + quad) * 8) ^ swz)];
        S[mi] = __builtin_amdgcn_mfma_f32_16x16x32_bf16(kf, qf[s], S[mi], 0, 0, 0);
      }

    // ---- causal mask (diagonal tile only) ----
    if (kt == tq) {
#pragma unroll
      for (int mi = 0; mi < 4; ++mi)
#pragma unroll
        for (int r = 0; r < 4; ++r) {
          const int kg = kt * 64 + mi * 16 + quad * 4 + r;
          const int qg = qw0 + l15;
          if (kg > qg) S[mi][r] = -1e30f;
        }
    }

    // ---- online softmax (state per q = l15, duplicated across quads) ----
    float mx = -1e30f;
#pragma unroll
    for (int mi = 0; mi < 4; ++mi)
#pragma unroll
      for (int r = 0; r < 4; ++r) mx = fmaxf(mx, S[mi][r]);
    mx = fmaxf(mx, __shfl_xor(mx, 16));
    mx = fmaxf(mx, __shfl_xor(mx, 32));
    const float mn = fmaxf(m_s, mx);
    const float alpha = __expf(m_s - mn);
    float sum = 0.f;
#pragma unroll
    for (int mi = 0; mi < 4; ++mi)
#pragma unroll
      for (int r = 0; r < 4; ++r) {
        const float p = __expf(S[mi][r] - mn);
        S[mi][r] = p;
        sum += p;
      }
    sum += __shfl_xor(sum, 16);
    sum += __shfl_xor(sum, 32);
    m_s = mn;
    l_s = l_s * alpha + sum;
    // pack P -> LDS (row = q, col = kcol; per-wave-private rows, no barrier)
#pragma unroll
    for (int mi = 0; mi < 4; ++mi) {
      uint2 w2;
      w2.x = (unsigned)f2b(S[mi][0]) | ((unsigned)f2b(S[mi][1]) << 16);
      w2.y = (unsigned)f2b(S[mi][2]) | ((unsigned)f2b(S[mi][3]) << 16);
      *(uint2*)&Ps[(wave * 16 + l15) * 72 + mi * 16 + quad * 4] = w2;
    }

    // ---- PV: O += P . V ----
    bf8_t pf[2], vf[4][2];
#pragma unroll
    for (int s = 0; s < 2; ++s)
      pf[s] = *(const bf8_t*)&Ps[(wave * 16 + l15) * 72 + s * 32 + quad * 8];
#pragma unroll
    for (int n4 = 0; n4 < 4; ++n4)
#pragma unroll
      for (int s = 0; s < 2; ++s)
        vf[n4][s] = *(const bf8_t*)&Vt[(n4 * 16 + l15) * 64 + (((4 * s + quad) * 8) ^ swz)];
    float ar[4];
#pragma unroll
    for (int r = 0; r < 4; ++r) ar[r] = __shfl(alpha, quad * 4 + r);
#pragma unroll
    for (int n4 = 0; n4 < 4; ++n4) {
#pragma unroll
      for (int r = 0; r < 4; ++r) O[n4][r] *= ar[r];
#pragma unroll
      for (int s = 0; s < 2; ++s)
        O[n4] = __builtin_amdgcn_mfma_f32_16x16x32_bf16(pf[s], vf[n4][s], O[n4], 0, 0, 0);
    }
  }

  // ---- epilogue: O / l -> bf16 ----
  const float rc = 1.0f / l_s;
  float rr[4];
#pragma unroll
  for (int r = 0; r < 4; ++r) rr[r] = __shfl(rc, quad * 4 + r);
#pragma unroll
  for (int n4 = 0; n4 < 4; ++n4)
#pragma unroll
    for (int r = 0; r < 4; ++r) {
      const int qg = tq * 64 + wave * 16 + quad * 4 + r;
      o[(size_t)(b * 2048 + qg) * 1024 + h * 64 + n4 * 16 + l15] = f2b(O[n4][r] * rr[r]);
    }
}

// ---------------- launcher ----------------
extern "C" void kernel_launch(void* const* d_in, const int* in_sizes, int n_in,
                              void* d_out, int out_size, void* d_ws, size_t ws_size,
                              hipStream_t stream) {
  const float* x = (const float*)d_in[0];
  const float* w_in = (const float*)d_in[1];
  const float* w_out = (const float*)d_in[2];
  const float* w_fc = (const float*)d_in[3];
  const float* b_fc = (const float*)d_in[4];
  const float* w_proj = (const float*)d_in[5];
  const float* b_proj = (const float*)d_in[6];
  float* out = (float*)d_out;

  char* ws = (char*)d_ws;
  unsigned short* w_in_b = (unsigned short*)(ws);                  // 0-6MB
  unsigned short* w_out_b = (unsigned short*)(ws + 6291456);       // 6-8MB
  unsigned short* w_fc_b = (unsigned short*)(ws + 8388608);        // 8-16MB
  unsigned short* w_proj_b = (unsigned short*)(ws + 16777216);     // 16-24MB
  unsigned short* h_b = (unsigned short*)(ws + 25165824);          // 24-32MB (ln1, ln2)
  float* x2 = (float*)(ws + 33554432);                             // 32-48MB
  unsigned short* qkv_b = (unsigned short*)(ws + 50331648);        // 48-72MB
  unsigned short* o_b = (unsigned short*)(ws + 75497472);          // 72-80MB
  unsigned short* m_b = (unsigned short*)(ws + 50331648);          // 48-80MB alias (dead qkv+o)
  // pack buffers alias regions dead between qkv-gemm and attn:
  unsigned short* Kp = (unsigned short*)(ws + 25165824);           // aliases h_b (8MB)
  unsigned short* Vp = (unsigned short*)(ws + 33554432);           // aliases x2 first half (8MB)

  f2b_kernel<<<3072, 256, 0, stream>>>(w_in, w_in_b, 3145728);
  f2b_kernel<<<1024, 256, 0, stream>>>(w_out, w_out_b, 1048576);
  f2b_kernel<<<4096, 256, 0, stream>>>(w_fc, w_fc_b, 4194304);
  f2b_kernel<<<4096, 256, 0, stream>>>(w_proj, w_proj_b, 4194304);

  ln_kernel<<<4096, 256, 0, stream>>>(x, h_b);

  gemm_bt<0><<<dim3(32, 24), 256, 0, stream>>>(h_b, w_in_b, 4096, 3072, 1024,
                                               nullptr, nullptr, nullptr, qkv_b);

  pack_kv<<<1024, 256, 0, stream>>>(qkv_b, Kp, Vp);

  attn_kernel<<<1024, 256, 0, stream>>>(qkv_b, Kp, Vp, o_b);

  gemm_bt<1><<<dim3(32, 8), 256, 0, stream>>>(o_b, w_out_b, 4096, 1024, 1024,
                                              nullptr, x, x2, nullptr);

  ln_kernel<<<4096, 256, 0, stream>>>(x2, h_b);

  gemm_bt<2><<<dim3(32, 32), 256, 0, stream>>>(h_b, w_fc_b, 4096, 4096, 1024,
                                               b_fc, nullptr, nullptr, m_b);

  gemm_bt<3><<<dim3(32, 8), 256, 0, stream>>>(m_b, w_proj_b, 4096, 1024, 4096,
                                              b_proj, x2, out, nullptr);
}

// Round 5
// 360.914 us; speedup vs baseline: 4.4504x; 1.0021x over previous
//
#include <hip/hip_runtime.h>
#include <stdint.h>

#define AS1 __attribute__((address_space(1)))
#define AS3 __attribute__((address_space(3)))

typedef __bf16 bf8_t __attribute__((ext_vector_type(8)));
typedef float f4_t __attribute__((ext_vector_type(4)));

// ---------------- helpers ----------------
__device__ __forceinline__ unsigned short f2b(float f) {
  unsigned u = __builtin_bit_cast(unsigned, f);
  u += 0x7fffu + ((u >> 16) & 1u);          // RNE
  return (unsigned short)(u >> 16);
}
__device__ __forceinline__ void unpack8(uint4 u, float* dst) {
  unsigned a0 = u.x, a1 = u.y, a2 = u.z, a3 = u.w;
  dst[0] = __builtin_bit_cast(float, a0 << 16);
  dst[1] = __builtin_bit_cast(float, a0 & 0xffff0000u);
  dst[2] = __builtin_bit_cast(float, a1 << 16);
  dst[3] = __builtin_bit_cast(float, a1 & 0xffff0000u);
  dst[4] = __builtin_bit_cast(float, a2 << 16);
  dst[5] = __builtin_bit_cast(float, a2 & 0xffff0000u);
  dst[6] = __builtin_bit_cast(float, a3 << 16);
  dst[7] = __builtin_bit_cast(float, a3 & 0xffff0000u);
}

// ---------------- f32 -> bf16 convert ----------------
__global__ __launch_bounds__(256) void f2b_kernel(const float* __restrict__ in,
                                                  unsigned short* __restrict__ out, int n) {
  int i = (blockIdx.x * 256 + threadIdx.x) * 4;
  if (i >= n) return;
  float4 v = *(const float4*)(in + i);
  union { unsigned short u[4]; uint2 d; } p;
  p.u[0] = f2b(v.x); p.u[1] = f2b(v.y); p.u[2] = f2b(v.z); p.u[3] = f2b(v.w);
  *(uint2*)(out + i) = p.d;
}

// ---------------- LayerNorm (E=1024), f32 in -> bf16 out ----------------
__global__ __launch_bounds__(256) void ln_kernel(const float* __restrict__ x,
                                                 unsigned short* __restrict__ out) {
  const int row = blockIdx.x, tid = threadIdx.x;
  const float* xr = x + (size_t)row * 1024;
  float4 v = ((const float4*)xr)[tid];
  float s = v.x + v.y + v.z + v.w;
  float q = v.x * v.x + v.y * v.y + v.z * v.z + v.w * v.w;
  for (int o = 32; o; o >>= 1) { s += __shfl_down(s, o); q += __shfl_down(q, o); }
  __shared__ float rs[4], rq[4];
  const int w = tid >> 6;
  if ((tid & 63) == 0) { rs[w] = s; rq[w] = q; }
  __syncthreads();
  s = rs[0] + rs[1] + rs[2] + rs[3];
  q = rq[0] + rq[1] + rq[2] + rq[3];
  const float mean = s * (1.0f / 1024.0f);
  const float var = q * (1.0f / 1024.0f) - mean * mean;
  const float rstd = rsqrtf(var + 1e-5f);
  union { unsigned short u[4]; uint2 d; } p;
  p.u[0] = f2b((v.x - mean) * rstd);
  p.u[1] = f2b((v.y - mean) * rstd);
  p.u[2] = f2b((v.z - mean) * rstd);
  p.u[3] = f2b((v.w - mean) * rstd);
  *(uint2*)(out + (size_t)row * 1024 + tid * 4) = p.d;
}

// ---------------- GEMM: C[M,N] = A[M,K] @ W[N,K]^T (bf16 in, fp32 acc) ------
// BM x 128 tile (BM = 128 or 64). BM=64 doubles block count for small-N GEMMs
// (2 blocks/CU -> cross-block overlap hides the barrier drain).
// EPI: 0 = store bf16; 1 = +resid -> f32; 2 = +bias, relu -> bf16; 3 = +bias +resid -> f32
template <int EPI, int BM>
__global__ __launch_bounds__(256, 2) void gemm_bt(
    const unsigned short* __restrict__ A, const unsigned short* __restrict__ Bw,
    int M, int N, int K,
    const float* __restrict__ bias, const float* __restrict__ resid,
    float* __restrict__ outF, unsigned short* __restrict__ outB) {
  constexpr int MI = BM / 32;          // m-frags per wave
  constexpr int NCH = (BM + 128) / 16; // 16-row staging chunks
  constexpr int PC = NCH / 4;          // chunks per wave
  __shared__ unsigned short As[BM * 32];
  __shared__ unsigned short Bs[128 * 32];
  const int tid = threadIdx.x;
  const int wave = tid >> 6, lane = tid & 63;
  const int bm = blockIdx.x, bn = blockIdx.y;
  const int wm = (wave & 1) * (BM / 2), wn = (wave >> 1) * 64;
  const int l16 = lane & 15, quad = lane >> 4;
  const int srow = lane >> 2;
  const int scol = (lane & 3) * 8;

  const unsigned short* Abase = A + (size_t)(bm * BM) * K;
  const unsigned short* Bbase = Bw + (size_t)(bn * 128) * K;

  f4_t acc[MI][4];
#pragma unroll
  for (int i = 0; i < MI; ++i)
#pragma unroll
    for (int j = 0; j < 4; ++j) acc[i][j] = (f4_t){0.f, 0.f, 0.f, 0.f};

  const int kiters = K >> 5;
  for (int k0 = 0; k0 < kiters; ++k0) {
    const int kk = k0 * 32;
#pragma unroll
    for (int i = 0; i < PC; ++i) {
      const int c = wave * PC + i;
      if (c < BM / 16) {
        const unsigned short* ga = Abase + (size_t)(c * 16 + srow) * K + kk + scol;
        __builtin_amdgcn_global_load_lds((const AS1 void*)ga, (AS3 void*)(As + c * 512), 16, 0, 0);
      } else {
        const int c2 = c - BM / 16;
        const unsigned short* gb = Bbase + (size_t)(c2 * 16 + srow) * K + kk + scol;
        __builtin_amdgcn_global_load_lds((const AS1 void*)gb, (AS3 void*)(Bs + c2 * 512), 16, 0, 0);
      }
    }
    __syncthreads();
    bf8_t af[MI], bfr[4];
#pragma unroll
    for (int mi = 0; mi < MI; ++mi)
      af[mi] = *(const bf8_t*)&As[(wm + mi * 16 + l16) * 32 + quad * 8];
#pragma unroll
    for (int ni = 0; ni < 4; ++ni)
      bfr[ni] = *(const bf8_t*)&Bs[(wn + ni * 16 + l16) * 32 + quad * 8];
#pragma unroll
    for (int mi = 0; mi < MI; ++mi)
#pragma unroll
      for (int ni = 0; ni < 4; ++ni)
        acc[mi][ni] =
            __builtin_amdgcn_mfma_f32_16x16x32_bf16(af[mi], bfr[ni], acc[mi][ni], 0, 0, 0);
    __syncthreads();
  }

#pragma unroll
  for (int mi = 0; mi < MI; ++mi) {
#pragma unroll
    for (int ni = 0; ni < 4; ++ni) {
      const int gm0 = bm * BM + wm + mi * 16 + quad * 4;
      const int gn = bn * 128 + wn + ni * 16 + l16;
#pragma unroll
      for (int r = 0; r < 4; ++r) {
        float v = acc[mi][ni][r];
        const size_t idx = (size_t)(gm0 + r) * N + gn;
        if (EPI == 0) {
          outB[idx] = f2b(v);
        } else if (EPI == 1) {
          outF[idx] = v + resid[idx];
        } else if (EPI == 2) {
          v += bias[gn];
          outB[idx] = f2b(fmaxf(v, 0.0f));
        } else {
          v += bias[gn];
          outF[idx] = v + resid[idx];
        }
      }
    }
  }
}

// ---------------- K/V tile pre-pack ----------------
// grid 1024 = (b,h,kt); builds contiguous 8KB tiles that are byte-exact LDS
// images for global_load_lds staging in attn.
__global__ __launch_bounds__(256) void pack_kv(const unsigned short* __restrict__ qkv,
                                               unsigned short* __restrict__ Kp,
                                               unsigned short* __restrict__ Vp) {
  const int lin = blockIdx.x;
  const int kt = lin & 31, h = (lin >> 5) & 15, b = lin >> 9;
  const int tid = threadIdx.x;
  __shared__ unsigned short Vs[64 * 72];
  const size_t rowbase = (size_t)(b * 2048 + kt * 64) * 3072 + h * 64;
  unsigned short* Kt = Kp + (size_t)lin * 4096;
  unsigned short* Vt = Vp + (size_t)lin * 4096;

  const int r0 = tid >> 3, cin = tid & 7;
#pragma unroll
  for (int it = 0; it < 2; ++it) {
    const int r = r0 + it * 32;
    uint4 ku = *(const uint4*)(qkv + rowbase + (size_t)r * 3072 + 1024 + cin * 8);
    float f[8]; unpack8(ku, f);
    union { unsigned short us[8]; uint4 v; } pk;
#pragma unroll
    for (int j = 0; j < 8; ++j) pk.us[j] = f2b(f[j] * 0.125f);
    *(uint4*)(Kt + (size_t)(r * 8 + (cin ^ (r & 7))) * 8) = pk.v;
    uint4 vu = *(const uint4*)(qkv + rowbase + (size_t)r * 3072 + 2048 + cin * 8);
    *(uint4*)&Vs[r * 72 + cin * 8] = vu;
  }
  __syncthreads();
#pragma unroll
  for (int oc2 = 0; oc2 < 2; ++oc2) {
    const int oc = tid * 2 + oc2;
    const int d = oc >> 3, c = oc & 7;
    const int k0 = 8 * (c ^ (d & 7));
    union { unsigned short us[8]; uint4 v; } pk;
#pragma unroll
    for (int j = 0; j < 8; ++j) pk.us[j] = Vs[(k0 + j) * 72 + d];
    *(uint4*)(Vt + (size_t)oc * 8) = pk.v;
  }
}

// ---------------- MFMA causal flash attention ----------------
// 1D grid 1024: b=lin&1, h=(lin>>1)&15, tq=lin>>5. Blocks sharing a CU get
// spread tq values -> balanced per-CU work. K/V staged via global_load_lds
// from pre-packed swizzled tiles.
__global__ __launch_bounds__(256, 4) void attn_kernel(const unsigned short* __restrict__ qkv,
                                                      const unsigned short* __restrict__ Kp,
                                                      const unsigned short* __restrict__ Vp,
                                                      unsigned short* __restrict__ o) {
  const int lin = blockIdx.x;
  const int b = lin & 1, h = (lin >> 1) & 15, tq = lin >> 5;
  const int tid = threadIdx.x;
  const int wave = tid >> 6, lane = tid & 63;
  const int l15 = lane & 15, quad = lane >> 4;

  __shared__ __align__(16) unsigned short Ks[64 * 64];
  __shared__ __align__(16) unsigned short Vt[64 * 64];
  __shared__ __align__(16) unsigned short Ps[64 * 72];

  bf8_t qf[2];
  {
    const int qrow = b * 2048 + tq * 64 + wave * 16 + l15;
#pragma unroll
    for (int s = 0; s < 2; ++s) {
      union { uint4 u; bf8_t v; } pk;
      pk.u = *(const uint4*)(qkv + (size_t)qrow * 3072 + h * 64 + s * 32 + quad * 8);
      qf[s] = pk.v;
    }
  }

  float m_s = -1e30f, l_s = 0.f;
  f4_t O[4];
#pragma unroll
  for (int j = 0; j < 4; ++j) O[j] = (f4_t){0.f, 0.f, 0.f, 0.f};

  const int qw0 = tq * 64 + wave * 16;
  const int swz = (l15 & 7) * 8;
  const size_t tile0 = (size_t)((b * 16 + h) * 32) * 4096;

  for (int kt = 0; kt <= tq; ++kt) {
    __syncthreads();
    const unsigned short* Ktile = Kp + tile0 + (size_t)kt * 4096;
    const unsigned short* Vtile = Vp + tile0 + (size_t)kt * 4096;
#pragma unroll
    for (int i = 0; i < 2; ++i) {
      const int seg = wave * 2 + i;
      __builtin_amdgcn_global_load_lds((const AS1 void*)(Ktile + seg * 512 + lane * 8),
                                       (AS3 void*)(Ks + seg * 512), 16, 0, 0);
      __builtin_amdgcn_global_load_lds((const AS1 void*)(Vtile + seg * 512 + lane * 8),
                                       (AS3 void*)(Vt + seg * 512), 16, 0, 0);
    }
    __syncthreads();

    f4_t S[4];
#pragma unroll
    for (int mi = 0; mi < 4; ++mi) S[mi] = (f4_t){0.f, 0.f, 0.f, 0.f};
#pragma unroll
    for (int s = 0; s < 2; ++s)
#pragma unroll
      for (int mi = 0; mi < 4; ++mi) {
        bf8_t kf = *(const bf8_t*)&Ks[(mi * 16 + l15) * 64 + (((4 * s + quad) * 8) ^ swz)];
        S[mi] = __builtin_amdgcn_mfma_f32_16x16x32_bf16(kf, qf[s], S[mi], 0, 0, 0);
      }

    if (kt == tq) {
#pragma unroll
      for (int mi = 0; mi < 4; ++mi)
#pragma unroll
        for (int r = 0; r < 4; ++r) {
          const int kg = kt * 64 + mi * 16 + quad * 4 + r;
          const int qg = qw0 + l15;
          if (kg > qg) S[mi][r] = -1e30f;
        }
    }

    float mx = -1e30f;
#pragma unroll
    for (int mi = 0; mi < 4; ++mi)
#pragma unroll
      for (int r = 0; r < 4; ++r) mx = fmaxf(mx, S[mi][r]);
    mx = fmaxf(mx, __shfl_xor(mx, 16));
    mx = fmaxf(mx, __shfl_xor(mx, 32));
    const float mn = fmaxf(m_s, mx);
    const float alpha = __expf(m_s - mn);
    float sum = 0.f;
#pragma unroll
    for (int mi = 0; mi < 4; ++mi)
#pragma unroll
      for (int r = 0; r < 4; ++r) {
        const float p = __expf(S[mi][r] - mn);
        S[mi][r] = p;
        sum += p;
      }
    sum += __shfl_xor(sum, 16);
    sum += __shfl_xor(sum, 32);
    m_s = mn;
    l_s = l_s * alpha + sum;
#pragma unroll
    for (int mi = 0; mi < 4; ++mi) {
      uint2 w2;
      w2.x = (unsigned)f2b(S[mi][0]) | ((unsigned)f2b(S[mi][1]) << 16);
      w2.y = (unsigned)f2b(S[mi][2]) | ((unsigned)f2b(S[mi][3]) << 16);
      *(uint2*)&Ps[(wave * 16 + l15) * 72 + mi * 16 + quad * 4] = w2;
    }

    bf8_t pf[2], vf[4][2];
#pragma unroll
    for (int s = 0; s < 2; ++s)
      pf[s] = *(const bf8_t*)&Ps[(wave * 16 + l15) * 72 + s * 32 + quad * 8];
#pragma unroll
    for (int n4 = 0; n4 < 4; ++n4)
#pragma unroll
      for (int s = 0; s < 2; ++s)
        vf[n4][s] = *(const bf8_t*)&Vt[(n4 * 16 + l15) * 64 + (((4 * s + quad) * 8) ^ swz)];
    float ar[4];
#pragma unroll
    for (int r = 0; r < 4; ++r) ar[r] = __shfl(alpha, quad * 4 + r);
#pragma unroll
    for (int n4 = 0; n4 < 4; ++n4) {
#pragma unroll
      for (int r = 0; r < 4; ++r) O[n4][r] *= ar[r];
#pragma unroll
      for (int s = 0; s < 2; ++s)
        O[n4] = __builtin_amdgcn_mfma_f32_16x16x32_bf16(pf[s], vf[n4][s], O[n4], 0, 0, 0);
    }
  }

  const float rc = 1.0f / l_s;
  float rr[4];
#pragma unroll
  for (int r = 0; r < 4; ++r) rr[r] = __shfl(rc, quad * 4 + r);
#pragma unroll
  for (int n4 = 0; n4 < 4; ++n4)
#pragma unroll
    for (int r = 0; r < 4; ++r) {
      const int qg = tq * 64 + wave * 16 + quad * 4 + r;
      o[(size_t)(b * 2048 + qg) * 1024 + h * 64 + n4 * 16 + l15] = f2b(O[n4][r] * rr[r]);
    }
}

// ---------------- launcher ----------------
extern "C" void kernel_launch(void* const* d_in, const int* in_sizes, int n_in,
                              void* d_out, int out_size, void* d_ws, size_t ws_size,
                              hipStream_t stream) {
  const float* x = (const float*)d_in[0];
  const float* w_in = (const float*)d_in[1];
  const float* w_out = (const float*)d_in[2];
  const float* w_fc = (const float*)d_in[3];
  const float* b_fc = (const float*)d_in[4];
  const float* w_proj = (const float*)d_in[5];
  const float* b_proj = (const float*)d_in[6];
  float* out = (float*)d_out;

  char* ws = (char*)d_ws;
  unsigned short* w_in_b = (unsigned short*)(ws);                  // 0-6MB
  unsigned short* w_out_b = (unsigned short*)(ws + 6291456);       // 6-8MB
  unsigned short* w_fc_b = (unsigned short*)(ws + 8388608);        // 8-16MB
  unsigned short* w_proj_b = (unsigned short*)(ws + 16777216);     // 16-24MB
  unsigned short* h_b = (unsigned short*)(ws + 25165824);          // 24-32MB (ln1, ln2)
  float* x2 = (float*)(ws + 33554432);                             // 32-48MB
  unsigned short* qkv_b = (unsigned short*)(ws + 50331648);        // 48-72MB
  unsigned short* o_b = (unsigned short*)(ws + 75497472);          // 72-80MB
  unsigned short* m_b = (unsigned short*)(ws + 50331648);          // 48-80MB alias (dead qkv+o)
  unsigned short* Kp = (unsigned short*)(ws + 25165824);           // aliases h_b (8MB)
  unsigned short* Vp = (unsigned short*)(ws + 33554432);           // aliases x2 first half (8MB)

  f2b_kernel<<<3072, 256, 0, stream>>>(w_in, w_in_b, 3145728);
  f2b_kernel<<<1024, 256, 0, stream>>>(w_out, w_out_b, 1048576);
  f2b_kernel<<<4096, 256, 0, stream>>>(w_fc, w_fc_b, 4194304);
  f2b_kernel<<<4096, 256, 0, stream>>>(w_proj, w_proj_b, 4194304);

  ln_kernel<<<4096, 256, 0, stream>>>(x, h_b);

  gemm_bt<0, 128><<<dim3(32, 24), 256, 0, stream>>>(h_b, w_in_b, 4096, 3072, 1024,
                                                    nullptr, nullptr, nullptr, qkv_b);

  pack_kv<<<1024, 256, 0, stream>>>(qkv_b, Kp, Vp);

  attn_kernel<<<1024, 256, 0, stream>>>(qkv_b, Kp, Vp, o_b);

  gemm_bt<1, 64><<<dim3(64, 8), 256, 0, stream>>>(o_b, w_out_b, 4096, 1024, 1024,
                                                  nullptr, x, x2, nullptr);

  ln_kernel<<<4096, 256, 0, stream>>>(x2, h_b);

  gemm_bt<2, 128><<<dim3(32, 32), 256, 0, stream>>>(h_b, w_fc_b, 4096, 4096, 1024,
                                                    b_fc, nullptr, nullptr, m_b);

  gemm_bt<3, 64><<<dim3(64, 8), 256, 0, stream>>>(m_b, w_proj_b, 4096, 1024, 4096,
                                                  b_proj, x2, out, nullptr);
}